// Round 11
// baseline (1066.269 us; speedup 1.0000x reference)
//
#include <hip/hip_runtime.h>

#define N_NODES 50000
#define N_EDGES 800000
#define F_INP   32
#define HDIM    64
#define EDIM    16
#define COUT    40
#define NGRAPH  64
#define LDS_STRIDE 18   // floats per staged attr row: 16 + 2 pad (keeps b64 align, spreads banks)

typedef float v2f __attribute__((ext_vector_type(2)));

// batch is sorted ascending; find graph start offsets
__global__ void gstart_kernel(const int* __restrict__ batch, int* __restrict__ gstart,
                              int N, int G) {
    int n = blockIdx.x * 256 + threadIdx.x;
    if (n >= N) return;
    int g  = batch[n];
    int gp = (n == 0) ? -1 : batch[n - 1];
    for (int gg = gp + 1; gg <= g; gg++) gstart[gg] = n;
    if (n == N - 1) {
        for (int gg = g + 1; gg <= G; gg++) gstart[gg] = N;
    }
}

// ---------------------------------------------------------------- input linear
__global__ void lin_in_kernel(const float* __restrict__ x, const float* __restrict__ W,
                              const float* __restrict__ b, float* __restrict__ h, int N) {
    int tid = threadIdx.x;
    int c = tid & 63;
    float w[F_INP];
#pragma unroll
    for (int k = 0; k < F_INP; k++) w[k] = W[k * HDIM + c];
    int node = blockIdx.x * 4 + (tid >> 6);
    if (node >= N) return;
    const float4* xr = (const float4*)(x + (size_t)node * F_INP);
    float acc = b[c];
#pragma unroll
    for (int k4 = 0; k4 < F_INP / 4; k4++) {
        float4 xv = xr[k4];
        acc += xv.x * w[k4 * 4 + 0] + xv.y * w[k4 * 4 + 1]
             + xv.z * w[k4 * 4 + 2] + xv.w * w[k4 * 4 + 3];
    }
    h[(size_t)node * HDIM + c] = acc;
}

// ---------------------------------------------------------------- BN stats
template <int C>
__global__ void bn_stats_kernel(const float* __restrict__ x, float* __restrict__ stats, int N) {
    const int RPB = 256 / C;
    int tid = threadIdx.x;
    int c = tid % C;
    int row0 = blockIdx.x * RPB + tid / C;
    int stride = gridDim.x * RPB;
    float s = 0.f, ss = 0.f;
    for (int r = row0; r < N; r += stride) {
        float v = x[(size_t)r * C + c];
        s += v; ss += v * v;
    }
    __shared__ float ls[256], lss[256];
    ls[tid] = s; lss[tid] = ss;
    __syncthreads();
    if (tid < C) {
        for (int k = 1; k < RPB; k++) { s += ls[tid + k * C]; ss += lss[tid + k * C]; }
        atomicAdd(&stats[c], s);
        atomicAdd(&stats[C + c], ss);
    }
}

// ---------------------------------------------------------------- edge-parallel aggregation (UNSORTED)
// One wave per 64 consecutive edges IN NATURAL ORDER; one edge per lane
// (lane = channel). No sort pipeline at all: dst/src read coalesced from
// edge_index; the lane's attr row ea[p] is CONSECUTIVE across the wave
// (4 KB streaming block) instead of the sorted permutation's random 64B
// gathers. Per edge, the segment-flush is replaced by two coalesced 256B
// atomic row-adds to num/den — fire-and-forget (no return value, no waitcnt
// on the critical path); ~400K distinct lines, avg 16 adds/line -> no hotspot.
// Inner loop otherwise identical to the round-8-verified structure:
// LDS same-address broadcast (DS pipe), pk_fma dot, 8-edge rolled body.
__global__ __launch_bounds__(256) void edge_agg_kernel(
        const float* __restrict__ h, const int* __restrict__ src,
        const int* __restrict__ dst, const float* __restrict__ ea,
        const float* __restrict__ We, const float* __restrict__ be,
        const float* __restrict__ tptr, const float* __restrict__ stats,
        const float* __restrict__ gamma, const float* __restrict__ beta,
        float* __restrict__ num, float* __restrict__ den) {
    __shared__ float sA[4 * 64 * LDS_STRIDE];    // 4 waves x 64 edges x 18 f = 18 KB
    int tid = threadIdx.x;
    int c  = tid & 63;                       // channel == lane
    int wv = tid >> 6;
    // BN folded: z = relu(h*sc + sb)
    float inv = 1.0f / (float)N_NODES;
    float mu  = stats[c] * inv;
    float var = stats[HDIM + c] * inv - mu * mu;
    float sc  = rsqrtf(var + 1e-5f) * gamma[c];
    float sb  = beta[c] - mu * sc;
    v2f w2[8];
#pragma unroll
    for (int k = 0; k < 8; k++) {
        w2[k].x = We[(2 * k) * HDIM + c];
        w2[k].y = We[(2 * k + 1) * HDIM + c];
    }
    float bc = be[c];
    float tl2 = (*tptr) * 1.4426950408889634f;   // t * log2(e)

    // this lane's own edge p (natural order; grid sized so p < E always)
    int p = (blockIdx.x * 4 + wv) * 64 + c;
    int d_own = dst[p];                      // coalesced
    int s_own = src[p];                      // coalesced
    // stage own attr row to LDS (rows consecutive across lanes -> streaming)
    float* myrow = &sA[(wv * 64 + c) * LDS_STRIDE];
    {
        const float4* ar = (const float4*)(ea + (size_t)p * EDIM);
        float4 a0 = ar[0], a1 = ar[1], a2 = ar[2], a3 = ar[3];
        myrow[0]=a0.x;  myrow[1]=a0.y;  myrow[2]=a0.z;  myrow[3]=a0.w;
        myrow[4]=a1.x;  myrow[5]=a1.y;  myrow[6]=a1.z;  myrow[7]=a1.w;
        myrow[8]=a2.x;  myrow[9]=a2.y;  myrow[10]=a2.z; myrow[11]=a2.w;
        myrow[12]=a3.x; myrow[13]=a3.y; myrow[14]=a3.z; myrow[15]=a3.w;
    }
    __syncthreads();                         // staging visible (per-wave use only)

    const float* wrow = &sA[(size_t)wv * 64 * LDS_STRIDE];
#pragma unroll 1
    for (int jj = 0; jj < 64; jj += 8) {
        // issue 8 h-row gathers ahead (independent vector loads)
        float hv[8];
#pragma unroll
        for (int u = 0; u < 8; u++) {
            int su = __builtin_amdgcn_readlane(s_own, jj + u);
            hv[u] = h[(size_t)su * HDIM + c];
        }
#pragma unroll
        for (int u = 0; u < 8; u++) {
            int du = __builtin_amdgcn_readlane(d_own, jj + u);
            // broadcast attr row via same-address ds_read_b64 (DS pipe)
            const v2f* arow = (const v2f*)&wrow[(jj + u) * LDS_STRIDE];
            v2f acc2 = {bc, 0.f};
#pragma unroll
            for (int k2 = 0; k2 < 8; k2++)
                acc2 += arow[k2] * w2[k2];       // v_pk_fma_f32
            float acc = acc2.x + acc2.y;
            float zv = fmaxf(hv[u] * sc + sb, 0.f);
            float m  = fmaxf(zv + acc, 0.f) + 1e-7f;
            float ex = exp2f(m * tl2);
            size_t idx = (size_t)du * HDIM + c;
            atomicAdd(&num[idx], ex * m);        // fire-and-forget, coalesced row
            atomicAdd(&den[idx], ex);
        }
    }
}

// ---------------------------------------------------------------- MLP part 1
// Fused finalize: in = num/(den+eps) + relu(BN(h)); also self-cleans num/den
// to zero for the next layer (each idx touched exactly once).
__global__ __launch_bounds__(256) void mlp1_kernel(
        float* __restrict__ num, float* __restrict__ den,
        const float* __restrict__ h, const float* __restrict__ stats,
        const float* __restrict__ gamma, const float* __restrict__ beta,
        const float* __restrict__ W1, const float* __restrict__ b1,
        float* __restrict__ h1, int N) {
    __shared__ float sW[HDIM * 128];         // 32 KB
    __shared__ float srow[32 * 65];          // +1 pad breaks bank stride
    int tid = threadIdx.x;
    for (int i = tid; i < HDIM * 128; i += 256) sW[i] = W1[i];
    int base = blockIdx.x * 32;
    {
        int cc = tid & 63;                   // constant across the i-loop (256%64==0)
        float inv = 1.0f / (float)N_NODES;
        float mu  = stats[cc] * inv;
        float var = stats[HDIM + cc] * inv - mu * mu;
        float rs  = rsqrtf(var + 1e-5f);
        float ga  = gamma[cc], bb = beta[cc];
        for (int i = tid; i < 32 * HDIM; i += 256) {
            int r = i >> 6;
            int node = base + r;
            float v = 0.f;
            if (node < N) {
                size_t idx = (size_t)node * HDIM + cc;
                float hv = h[idx];
                float z  = fmaxf((hv - mu) * rs * ga + bb, 0.f);
                float nu = num[idx], de = den[idx];
                num[idx] = 0.f; den[idx] = 0.f;   // ready for next layer
                v = nu / (de + 1e-16f) + z;
            }
            srow[r * 65 + cc] = v;
        }
    }
    __syncthreads();
    int tx = tid & 31;                       // outputs 4*tx .. 4*tx+3
    int ty = tid >> 5;                       // nodes ty*4 .. ty*4+3
    float acc[4][4];
    float b0 = b1[4 * tx], bb1 = b1[4 * tx + 1], b2v = b1[4 * tx + 2], b3 = b1[4 * tx + 3];
#pragma unroll
    for (int j = 0; j < 4; j++) { acc[j][0] = b0; acc[j][1] = bb1; acc[j][2] = b2v; acc[j][3] = b3; }
#pragma unroll 8
    for (int k = 0; k < HDIM; k++) {
        float4 wv = *(const float4*)&sW[k * 128 + 4 * tx];
        float r0 = srow[(ty * 4 + 0) * 65 + k];
        float r1 = srow[(ty * 4 + 1) * 65 + k];
        float r2 = srow[(ty * 4 + 2) * 65 + k];
        float r3 = srow[(ty * 4 + 3) * 65 + k];
        acc[0][0] += r0 * wv.x; acc[0][1] += r0 * wv.y; acc[0][2] += r0 * wv.z; acc[0][3] += r0 * wv.w;
        acc[1][0] += r1 * wv.x; acc[1][1] += r1 * wv.y; acc[1][2] += r1 * wv.z; acc[1][3] += r1 * wv.w;
        acc[2][0] += r2 * wv.x; acc[2][1] += r2 * wv.y; acc[2][2] += r2 * wv.z; acc[2][3] += r2 * wv.w;
        acc[3][0] += r3 * wv.x; acc[3][1] += r3 * wv.y; acc[3][2] += r3 * wv.z; acc[3][3] += r3 * wv.w;
    }
#pragma unroll
    for (int j = 0; j < 4; j++) {
        int node = base + ty * 4 + j;
        if (node < N)
            *(float4*)&h1[(size_t)node * 128 + 4 * tx] =
                make_float4(acc[j][0], acc[j][1], acc[j][2], acc[j][3]);
    }
}

// ---------------------------------------------------------------- MLP part 2
__global__ __launch_bounds__(256) void mlp2_kernel(
        const float* __restrict__ h1, const float* __restrict__ stats,
        const float* __restrict__ mg, const float* __restrict__ mb,
        const float* __restrict__ W2, const float* __restrict__ b2,
        float* __restrict__ h, int N) {
    __shared__ float sW[128 * HDIM];         // 32 KB
    __shared__ float sact[32 * 129];         // 16.5 KB, +1 pad
    __shared__ float sbn[4 * 128];           // mu, rs, gamma, beta
    int tid = threadIdx.x;
    for (int i = tid; i < 128 * HDIM; i += 256) sW[i] = W2[i];
    if (tid < 128) {
        float inv = 1.0f / (float)N;
        float mu  = stats[tid] * inv;
        float var = stats[128 + tid] * inv - mu * mu;
        sbn[tid]       = mu;
        sbn[128 + tid] = rsqrtf(var + 1e-5f);
        sbn[256 + tid] = mg[tid];
        sbn[384 + tid] = mb[tid];
    }
    __syncthreads();
    int base = blockIdx.x * 32;
    for (int i = tid; i < 32 * 128; i += 256) {
        int r = i >> 7, o = i & 127;
        int node = base + r;
        float v = 0.f;
        if (node < N) {
            v = h1[(size_t)node * 128 + o];
            v = fmaxf((v - sbn[o]) * sbn[128 + o] * sbn[256 + o] + sbn[384 + o], 0.f);
        }
        sact[r * 129 + o] = v;
    }
    __syncthreads();
    int tx = tid & 15;                       // outputs 4*tx .. 4*tx+3
    int ty = tid >> 4;                       // nodes ty*2, ty*2+1
    float acc[2][4];
    float b0 = b2[4 * tx], bb1 = b2[4 * tx + 1], b2v = b2[4 * tx + 2], b3 = b2[4 * tx + 3];
    acc[0][0] = b0; acc[0][1] = bb1; acc[0][2] = b2v; acc[0][3] = b3;
    acc[1][0] = b0; acc[1][1] = bb1; acc[1][2] = b2v; acc[1][3] = b3;
#pragma unroll 8
    for (int k = 0; k < 128; k++) {
        float4 wv = *(const float4*)&sW[k * HDIM + 4 * tx];
        float r0 = sact[(ty * 2 + 0) * 129 + k];
        float r1 = sact[(ty * 2 + 1) * 129 + k];
        acc[0][0] += r0 * wv.x; acc[0][1] += r0 * wv.y; acc[0][2] += r0 * wv.z; acc[0][3] += r0 * wv.w;
        acc[1][0] += r1 * wv.x; acc[1][1] += r1 * wv.y; acc[1][2] += r1 * wv.z; acc[1][3] += r1 * wv.w;
    }
#pragma unroll
    for (int j = 0; j < 2; j++) {
        int node = base + ty * 2 + j;
        if (node < N) {
            float4* p = (float4*)&h[(size_t)node * HDIM + 4 * tx];
            float4 old = *p;
            *p = make_float4(old.x + acc[j][0], old.y + acc[j][1],
                             old.z + acc[j][2], old.w + acc[j][3]);
        }
    }
}

// ---------------------------------------------------------------- pool + head
__global__ void pool_out_kernel(const float* __restrict__ h, const int* __restrict__ gstart,
                                const float* __restrict__ Wo, const float* __restrict__ bo,
                                float* __restrict__ out, int N) {
    __shared__ float sp[HDIM];
    __shared__ float red[256];
    __shared__ float sW[HDIM * COUT];
    int g = blockIdx.x;
    int tid = threadIdx.x;
    for (int i = tid; i < HDIM * COUT; i += 256) sW[i] = Wo[i];
    int beg = gstart[g], end = gstart[g + 1];
    int c = tid & 63, r0 = tid >> 6;
    float s = 0.f;
    for (int r = beg + r0; r < end; r += 4) s += h[(size_t)r * HDIM + c];
    red[tid] = s;
    __syncthreads();
    if (tid < HDIM) {
        s = red[tid] + red[tid + 64] + red[tid + 128] + red[tid + 192];
        float cnt = (float)(end - beg);
        float pooled = s / fmaxf(cnt, 1.0f);
        sp[tid] = fmaxf(pooled, 0.0f);
    }
    __syncthreads();
    if (tid < COUT) {
        float acc = bo[tid];
#pragma unroll
        for (int k = 0; k < HDIM; k++) acc += sp[k] * sW[k * COUT + tid];
        out[g * COUT + tid] = acc;
    }
}

// ================================================================ launch
extern "C" void kernel_launch(void* const* d_in, const int* in_sizes, int n_in,
                              void* d_out, int out_size, void* d_ws, size_t ws_size,
                              hipStream_t stream) {
    (void)in_sizes; (void)n_in; (void)out_size; (void)ws_size;
    const float* x          = (const float*)d_in[0];
    const int*   eidx       = (const int*)  d_in[1];
    const float* eattr      = (const float*)d_in[2];
    const int*   batch      = (const int*)  d_in[3];
    const float* lin_in_w   = (const float*)d_in[4];
    const float* lin_in_b   = (const float*)d_in[5];
    const float* norm_gamma = (const float*)d_in[6];
    const float* norm_beta  = (const float*)d_in[7];
    const float* edge_w     = (const float*)d_in[8];
    const float* edge_b     = (const float*)d_in[9];
    const float* tparam     = (const float*)d_in[10];
    const float* mlp_w1     = (const float*)d_in[11];
    const float* mlp_b1     = (const float*)d_in[12];
    const float* mlp_gamma  = (const float*)d_in[13];
    const float* mlp_beta   = (const float*)d_in[14];
    const float* mlp_w2     = (const float*)d_in[15];
    const float* mlp_b2     = (const float*)d_in[16];
    const float* lin_out_w  = (const float*)d_in[17];
    const float* lin_out_b  = (const float*)d_in[18];
    float* out = (float*)d_out;

    const int* src = eidx;                   // edge_index[0]
    const int* dst = eidx + N_EDGES;         // edge_index[1]

    char* ws = (char*)d_ws;
    size_t off = 0;
    auto alloc = [&](size_t bytes) -> char* {
        char* p = ws + off;
        off = (off + bytes + 255) & ~(size_t)255;
        return p;
    };
    // stats first (zero region)
    float* statsA0 = (float*)alloc(128 * 4);
    float* statsB0 = (float*)alloc(256 * 4);
    float* statsA1 = (float*)alloc(128 * 4);
    float* statsB1 = (float*)alloc(256 * 4);
    size_t zero_bytes = off;
    int*   gstart  = (int*)  alloc((size_t)(NGRAPH + 1) * 4);
    float* h       = (float*)alloc((size_t)N_NODES * HDIM * 4);
    float* num     = (float*)alloc((size_t)N_NODES * HDIM * 4);
    float* den     = (float*)alloc((size_t)N_NODES * HDIM * 4);   // contiguous after num
    float* h1      = (float*)alloc((size_t)N_NODES * 2 * HDIM * 4);

    hipMemsetAsync(d_ws, 0, zero_bytes, stream);                       // stats
    // num+den zeroed once; mlp1 self-cleans them for the next layer
    hipMemsetAsync(num, 0, (size_t)N_NODES * HDIM * 4 * 2, stream);

    const int NB = (N_NODES + 255) / 256;    // 196 blocks
    gstart_kernel <<<NB, 256, 0, stream>>>(batch, gstart, N_NODES, NGRAPH);
    lin_in_kernel <<<(N_NODES + 3) / 4, 256, 0, stream>>>(x, lin_in_w, lin_in_b, h, N_NODES);

    const int AGG_BLOCKS = N_EDGES / 256;    // 3125, exact (4 waves x 64 edges)

    float* statsA[2] = { statsA0, statsA1 };
    float* statsB[2] = { statsB0, statsB1 };
    for (int l = 0; l < 2; l++) {
        bn_stats_kernel<64><<<256, 256, 0, stream>>>(h, statsA[l], N_NODES);
        edge_agg_kernel<<<AGG_BLOCKS, 256, 0, stream>>>(
            h, src, dst, eattr,
            edge_w + (size_t)l * EDIM * HDIM, edge_b + l * HDIM,
            tparam + l, statsA[l], norm_gamma + l * HDIM, norm_beta + l * HDIM,
            num, den);
        mlp1_kernel<<<(N_NODES + 31) / 32, 256, 0, stream>>>(
            num, den, h, statsA[l], norm_gamma + l * HDIM, norm_beta + l * HDIM,
            mlp_w1 + (size_t)l * HDIM * 2 * HDIM, mlp_b1 + l * 2 * HDIM, h1, N_NODES);
        bn_stats_kernel<128><<<256, 256, 0, stream>>>(h1, statsB[l], N_NODES);
        mlp2_kernel<<<(N_NODES + 31) / 32, 256, 0, stream>>>(
            h1, statsB[l], mlp_gamma + l * 2 * HDIM, mlp_beta + l * 2 * HDIM,
            mlp_w2 + (size_t)l * 2 * HDIM * HDIM, mlp_b2 + l * HDIM, h, N_NODES);
    }
    pool_out_kernel<<<NGRAPH, 256, 0, stream>>>(h, gstart, lin_out_w, lin_out_b, out, N_NODES);
}

// Round 12
// 591.951 us; speedup vs baseline: 1.8013x; 1.8013x over previous
//
#include <hip/hip_runtime.h>

#define N_NODES 50000
#define N_EDGES 800000
#define F_INP   32
#define HDIM    64
#define EDIM    16
#define COUT    40
#define NGRAPH  64
#define LDS_STRIDE 18   // floats per staged attr row: 16 + 2 pad (keeps b64 align, spreads banks)
#define CPAD    16      // cursor/cnt padding: 1 counter per 64B line (kills same-line atomic serialization)

typedef float v2f __attribute__((ext_vector_type(2)));

// ---------------------------------------------------------------- sort by dst
// 4 edges/thread: 4 independent atomic chains (MLP vs latency), int4 reads.
__global__ void hist_kernel(const int* __restrict__ dst, int* __restrict__ cnt, int E) {
    int base = (blockIdx.x * 256 + threadIdx.x) * 4;
    if (base >= E) return;                   // E % 4 == 0
    int4 d4 = *(const int4*)(dst + base);
    atomicAdd(&cnt[(size_t)d4.x * CPAD], 1);
    atomicAdd(&cnt[(size_t)d4.y * CPAD], 1);
    atomicAdd(&cnt[(size_t)d4.z * CPAD], 1);
    atomicAdd(&cnt[(size_t)d4.w * CPAD], 1);
}

// 3-stage scan over the PADDED cnt array (stride CPAD); cursor also padded.
__global__ void scan_part_kernel(const int* __restrict__ cnt, int* __restrict__ bsum, int n) {
    __shared__ int red[256];
    int tid = threadIdx.x;
    int idx = blockIdx.x * 256 + tid;
    red[tid] = (idx < n) ? cnt[(size_t)idx * CPAD] : 0;
    __syncthreads();
    for (int off = 128; off > 0; off >>= 1) {
        if (tid < off) red[tid] += red[tid + off];
        __syncthreads();
    }
    if (tid == 0) bsum[blockIdx.x] = red[0];
}

__global__ void scan_top_kernel(int* __restrict__ bsum, int nb) {
    __shared__ int tmp[256];
    int tid = threadIdx.x;
    int v = (tid < nb) ? bsum[tid] : 0;
    tmp[tid] = v;
    __syncthreads();
    for (int off = 1; off < 256; off <<= 1) {
        int x = (tid >= off) ? tmp[tid - off] : 0;
        __syncthreads();
        tmp[tid] += x;
        __syncthreads();
    }
    if (tid < nb) bsum[tid] = tmp[tid] - v;   // exclusive
}

__global__ void scan_apply_kernel(const int* __restrict__ cnt, const int* __restrict__ bsum,
                                  int* __restrict__ cursor, int n) {
    __shared__ int tmp[256];
    int tid = threadIdx.x;
    int idx = blockIdx.x * 256 + tid;
    int v = (idx < n) ? cnt[(size_t)idx * CPAD] : 0;
    tmp[tid] = v;
    __syncthreads();
    for (int off = 1; off < 256; off <<= 1) {
        int x = (tid >= off) ? tmp[tid - off] : 0;
        __syncthreads();
        tmp[tid] += x;
        __syncthreads();
    }
    int excl = tmp[tid] - v + bsum[blockIdx.x];
    if (idx < n) cursor[(size_t)idx * CPAD] = excl;
}

// scatter packed: one int4 (dst, src, edge_id, 0) per sorted position.
// 4 edges/thread for 4-deep independent atomic->store chains.
__global__ void scatter_kernel(const int* __restrict__ dst, const int* __restrict__ src,
                               int* __restrict__ cursor, int4* __restrict__ edge4, int E) {
    int base = (blockIdx.x * 256 + threadIdx.x) * 4;
    if (base >= E) return;                   // E % 4 == 0
    int4 d4 = *(const int4*)(dst + base);
    int4 s4 = *(const int4*)(src + base);
    int p0 = atomicAdd(&cursor[(size_t)d4.x * CPAD], 1);
    int p1 = atomicAdd(&cursor[(size_t)d4.y * CPAD], 1);
    int p2 = atomicAdd(&cursor[(size_t)d4.z * CPAD], 1);
    int p3 = atomicAdd(&cursor[(size_t)d4.w * CPAD], 1);
    edge4[p0] = make_int4(d4.x, s4.x, base + 0, 0);
    edge4[p1] = make_int4(d4.y, s4.y, base + 1, 0);
    edge4[p2] = make_int4(d4.z, s4.z, base + 2, 0);
    edge4[p3] = make_int4(d4.w, s4.w, base + 3, 0);
}

// batch is sorted ascending; find graph start offsets
__global__ void gstart_kernel(const int* __restrict__ batch, int* __restrict__ gstart,
                              int N, int G) {
    int n = blockIdx.x * 256 + threadIdx.x;
    if (n >= N) return;
    int g  = batch[n];
    int gp = (n == 0) ? -1 : batch[n - 1];
    for (int gg = gp + 1; gg <= g; gg++) gstart[gg] = n;
    if (n == N - 1) {
        for (int gg = g + 1; gg <= G; gg++) gstart[gg] = N;
    }
}

// ---------------------------------------------------------------- input linear
__global__ void lin_in_kernel(const float* __restrict__ x, const float* __restrict__ W,
                              const float* __restrict__ b, float* __restrict__ h, int N) {
    int tid = threadIdx.x;
    int c = tid & 63;
    float w[F_INP];
#pragma unroll
    for (int k = 0; k < F_INP; k++) w[k] = W[k * HDIM + c];
    int node = blockIdx.x * 4 + (tid >> 6);
    if (node >= N) return;
    const float4* xr = (const float4*)(x + (size_t)node * F_INP);
    float acc = b[c];
#pragma unroll
    for (int k4 = 0; k4 < F_INP / 4; k4++) {
        float4 xv = xr[k4];
        acc += xv.x * w[k4 * 4 + 0] + xv.y * w[k4 * 4 + 1]
             + xv.z * w[k4 * 4 + 2] + xv.w * w[k4 * 4 + 3];
    }
    h[(size_t)node * HDIM + c] = acc;
}

// ---------------------------------------------------------------- BN stats
template <int C>
__global__ void bn_stats_kernel(const float* __restrict__ x, float* __restrict__ stats, int N) {
    const int RPB = 256 / C;
    int tid = threadIdx.x;
    int c = tid % C;
    int row0 = blockIdx.x * RPB + tid / C;
    int stride = gridDim.x * RPB;
    float s = 0.f, ss = 0.f;
    for (int r = row0; r < N; r += stride) {
        float v = x[(size_t)r * C + c];
        s += v; ss += v * v;
    }
    __shared__ float ls[256], lss[256];
    ls[tid] = s; lss[tid] = ss;
    __syncthreads();
    if (tid < C) {
        for (int k = 1; k < RPB; k++) { s += ls[tid + k * C]; ss += lss[tid + k * C]; }
        atomicAdd(&stats[c], s);
        atomicAdd(&stats[C + c], ss);
    }
}

// ---------------------------------------------------------------- edge-parallel aggregation
// One wave per 64 contiguous dst-sorted positions; ONE EDGE PER LANE.
// Attr rows staged in LDS; broadcast via same-address ds_read_b64 (DS pipe).
// pk_fma dot, ballot boundary mask (SALU in-loop test), 8-edge rolled body.
// Sorted order is essential: it amortizes the num/den flush atomics to
// ~62K*2 row-adds (32 MB). Round-11 measured the unsorted alternative at
// 400 MB of atomic write traffic (L2-thrash across XCDs) -> 326 us. Keep sort.
__global__ __launch_bounds__(256) void edge_agg_kernel(
        const float* __restrict__ h, const float* __restrict__ ea,
        const int4* __restrict__ edge4,
        const float* __restrict__ We, const float* __restrict__ be,
        const float* __restrict__ tptr, const float* __restrict__ stats,
        const float* __restrict__ gamma, const float* __restrict__ beta,
        float* __restrict__ num, float* __restrict__ den) {
    __shared__ float sA[4 * 64 * LDS_STRIDE];    // 4 waves x 64 edges x 18 f = 18 KB
    int tid = threadIdx.x;
    int c  = tid & 63;                       // channel == lane
    int wv = tid >> 6;
    // BN folded: z = relu(h*sc + sb)
    float inv = 1.0f / (float)N_NODES;
    float mu  = stats[c] * inv;
    float var = stats[HDIM + c] * inv - mu * mu;
    float sc  = rsqrtf(var + 1e-5f) * gamma[c];
    float sb  = beta[c] - mu * sc;
    v2f w2[8];
#pragma unroll
    for (int k = 0; k < 8; k++) {
        w2[k].x = We[(2 * k) * HDIM + c];
        w2[k].y = We[(2 * k + 1) * HDIM + c];
    }
    float bc = be[c];
    float tl2 = (*tptr) * 1.4426950408889634f;   // t * log2(e)

    // this lane's own edge (position p in sorted order)
    int p = (blockIdx.x * 4 + wv) * 64 + c;      // grid sized so p < E always
    int4 pk = edge4[p];                          // one coalesced dwordx4
    int d_own = pk.x;
    int s_own = pk.y;
    int e     = pk.z;
    // stage own attr row to LDS
    float* myrow = &sA[(wv * 64 + c) * LDS_STRIDE];
    {
        const float4* ar = (const float4*)(ea + (size_t)e * EDIM);
        float4 a0 = ar[0], a1 = ar[1], a2 = ar[2], a3 = ar[3];
        myrow[0]=a0.x;  myrow[1]=a0.y;  myrow[2]=a0.z;  myrow[3]=a0.w;
        myrow[4]=a1.x;  myrow[5]=a1.y;  myrow[6]=a1.z;  myrow[7]=a1.w;
        myrow[8]=a2.x;  myrow[9]=a2.y;  myrow[10]=a2.z; myrow[11]=a2.w;
        myrow[12]=a3.x; myrow[13]=a3.y; myrow[14]=a3.z; myrow[15]=a3.w;
    }
    // boundary mask: bit u set iff dst changes at chunk position u (u>0)
    int dprev = __shfl_up(d_own, 1);
    unsigned long long bmask = __ballot(c > 0 && d_own != dprev);
    __syncthreads();                         // staging visible (per-wave use only)

    const float* wrow = &sA[(size_t)wv * 64 * LDS_STRIDE];
    float nacc = 0.f, dacc = 0.f;
    int cur_d = __builtin_amdgcn_readlane(d_own, 0);
#pragma unroll 1
    for (int jj = 0; jj < 64; jj += 8) {
        // issue 8 h-row gathers ahead (independent vector loads)
        float hv[8];
#pragma unroll
        for (int u = 0; u < 8; u++) {
            int su = __builtin_amdgcn_readlane(s_own, jj + u);
            hv[u] = h[(size_t)su * HDIM + c];
        }
#pragma unroll
        for (int u = 0; u < 8; u++) {
            if (bmask & (1ull << (jj + u))) {    // SALU test, wave-uniform
                atomicAdd(&num[(size_t)cur_d * HDIM + c], nacc);
                atomicAdd(&den[(size_t)cur_d * HDIM + c], dacc);
                nacc = 0.f; dacc = 0.f;
                cur_d = __builtin_amdgcn_readlane(d_own, jj + u);
            }
            // broadcast attr row via same-address ds_read_b64 (DS pipe)
            const v2f* arow = (const v2f*)&wrow[(jj + u) * LDS_STRIDE];
            v2f acc2 = {bc, 0.f};
#pragma unroll
            for (int k2 = 0; k2 < 8; k2++)
                acc2 += arow[k2] * w2[k2];       // v_pk_fma_f32
            float acc = acc2.x + acc2.y;
            float zv = fmaxf(hv[u] * sc + sb, 0.f);
            float m  = fmaxf(zv + acc, 0.f) + 1e-7f;
            float ex = exp2f(m * tl2);
            dacc += ex;
            nacc += ex * m;
        }
    }
    atomicAdd(&num[(size_t)cur_d * HDIM + c], nacc);
    atomicAdd(&den[(size_t)cur_d * HDIM + c], dacc);
}

// ---------------------------------------------------------------- MLP part 1
// Fused finalize: in = num/(den+eps) + relu(BN(h)); also self-cleans num/den
// to zero for the next layer (each idx touched exactly once).
__global__ __launch_bounds__(256) void mlp1_kernel(
        float* __restrict__ num, float* __restrict__ den,
        const float* __restrict__ h, const float* __restrict__ stats,
        const float* __restrict__ gamma, const float* __restrict__ beta,
        const float* __restrict__ W1, const float* __restrict__ b1,
        float* __restrict__ h1, int N) {
    __shared__ float sW[HDIM * 128];         // 32 KB
    __shared__ float srow[32 * 65];          // +1 pad breaks bank stride
    int tid = threadIdx.x;
    for (int i = tid; i < HDIM * 128; i += 256) sW[i] = W1[i];
    int base = blockIdx.x * 32;
    {
        int cc = tid & 63;                   // constant across the i-loop (256%64==0)
        float inv = 1.0f / (float)N_NODES;
        float mu  = stats[cc] * inv;
        float var = stats[HDIM + cc] * inv - mu * mu;
        float rs  = rsqrtf(var + 1e-5f);
        float ga  = gamma[cc], bb = beta[cc];
        for (int i = tid; i < 32 * HDIM; i += 256) {
            int r = i >> 6;
            int node = base + r;
            float v = 0.f;
            if (node < N) {
                size_t idx = (size_t)node * HDIM + cc;
                float hv = h[idx];
                float z  = fmaxf((hv - mu) * rs * ga + bb, 0.f);
                float nu = num[idx], de = den[idx];
                num[idx] = 0.f; den[idx] = 0.f;   // ready for next layer
                v = nu / (de + 1e-16f) + z;
            }
            srow[r * 65 + cc] = v;
        }
    }
    __syncthreads();
    int tx = tid & 31;                       // outputs 4*tx .. 4*tx+3
    int ty = tid >> 5;                       // nodes ty*4 .. ty*4+3
    float acc[4][4];
    float b0 = b1[4 * tx], bb1 = b1[4 * tx + 1], b2v = b1[4 * tx + 2], b3 = b1[4 * tx + 3];
#pragma unroll
    for (int j = 0; j < 4; j++) { acc[j][0] = b0; acc[j][1] = bb1; acc[j][2] = b2v; acc[j][3] = b3; }
#pragma unroll 8
    for (int k = 0; k < HDIM; k++) {
        float4 wv = *(const float4*)&sW[k * 128 + 4 * tx];
        float r0 = srow[(ty * 4 + 0) * 65 + k];
        float r1 = srow[(ty * 4 + 1) * 65 + k];
        float r2 = srow[(ty * 4 + 2) * 65 + k];
        float r3 = srow[(ty * 4 + 3) * 65 + k];
        acc[0][0] += r0 * wv.x; acc[0][1] += r0 * wv.y; acc[0][2] += r0 * wv.z; acc[0][3] += r0 * wv.w;
        acc[1][0] += r1 * wv.x; acc[1][1] += r1 * wv.y; acc[1][2] += r1 * wv.z; acc[1][3] += r1 * wv.w;
        acc[2][0] += r2 * wv.x; acc[2][1] += r2 * wv.y; acc[2][2] += r2 * wv.z; acc[2][3] += r2 * wv.w;
        acc[3][0] += r3 * wv.x; acc[3][1] += r3 * wv.y; acc[3][2] += r3 * wv.z; acc[3][3] += r3 * wv.w;
    }
#pragma unroll
    for (int j = 0; j < 4; j++) {
        int node = base + ty * 4 + j;
        if (node < N)
            *(float4*)&h1[(size_t)node * 128 + 4 * tx] =
                make_float4(acc[j][0], acc[j][1], acc[j][2], acc[j][3]);
    }
}

// ---------------------------------------------------------------- MLP part 2
__global__ __launch_bounds__(256) void mlp2_kernel(
        const float* __restrict__ h1, const float* __restrict__ stats,
        const float* __restrict__ mg, const float* __restrict__ mb,
        const float* __restrict__ W2, const float* __restrict__ b2,
        float* __restrict__ h, int N) {
    __shared__ float sW[128 * HDIM];         // 32 KB
    __shared__ float sact[32 * 129];         // 16.5 KB, +1 pad
    __shared__ float sbn[4 * 128];           // mu, rs, gamma, beta
    int tid = threadIdx.x;
    for (int i = tid; i < 128 * HDIM; i += 256) sW[i] = W2[i];
    if (tid < 128) {
        float inv = 1.0f / (float)N;
        float mu  = stats[tid] * inv;
        float var = stats[128 + tid] * inv - mu * mu;
        sbn[tid]       = mu;
        sbn[128 + tid] = rsqrtf(var + 1e-5f);
        sbn[256 + tid] = mg[tid];
        sbn[384 + tid] = mb[tid];
    }
    __syncthreads();
    int base = blockIdx.x * 32;
    for (int i = tid; i < 32 * 128; i += 256) {
        int r = i >> 7, o = i & 127;
        int node = base + r;
        float v = 0.f;
        if (node < N) {
            v = h1[(size_t)node * 128 + o];
            v = fmaxf((v - sbn[o]) * sbn[128 + o] * sbn[256 + o] + sbn[384 + o], 0.f);
        }
        sact[r * 129 + o] = v;
    }
    __syncthreads();
    int tx = tid & 15;                       // outputs 4*tx .. 4*tx+3
    int ty = tid >> 4;                       // nodes ty*2, ty*2+1
    float acc[2][4];
    float b0 = b2[4 * tx], bb1 = b2[4 * tx + 1], b2v = b2[4 * tx + 2], b3 = b2[4 * tx + 3];
    acc[0][0] = b0; acc[0][1] = bb1; acc[0][2] = b2v; acc[0][3] = b3;
    acc[1][0] = b0; acc[1][1] = bb1; acc[1][2] = b2v; acc[1][3] = b3;
#pragma unroll 8
    for (int k = 0; k < 128; k++) {
        float4 wv = *(const float4*)&sW[k * HDIM + 4 * tx];
        float r0 = sact[(ty * 2 + 0) * 129 + k];
        float r1 = sact[(ty * 2 + 1) * 129 + k];
        acc[0][0] += r0 * wv.x; acc[0][1] += r0 * wv.y; acc[0][2] += r0 * wv.z; acc[0][3] += r0 * wv.w;
        acc[1][0] += r1 * wv.x; acc[1][1] += r1 * wv.y; acc[1][2] += r1 * wv.z; acc[1][3] += r1 * wv.w;
    }
#pragma unroll
    for (int j = 0; j < 2; j++) {
        int node = base + ty * 2 + j;
        if (node < N) {
            float4* p = (float4*)&h[(size_t)node * HDIM + 4 * tx];
            float4 old = *p;
            *p = make_float4(old.x + acc[j][0], old.y + acc[j][1],
                             old.z + acc[j][2], old.w + acc[j][3]);
        }
    }
}

// ---------------------------------------------------------------- pool + head
// 64 blocks only (low TLP) -> the row loop is latency-bound. 4 independent
// accumulators (rows r, r+4, r+8, r+12; step 16) quarter the dependent-load
// chain; identical row set per lane as the step-4 loop.
__global__ void pool_out_kernel(const float* __restrict__ h, const int* __restrict__ gstart,
                                const float* __restrict__ Wo, const float* __restrict__ bo,
                                float* __restrict__ out, int N) {
    __shared__ float sp[HDIM];
    __shared__ float red[256];
    __shared__ float sW[HDIM * COUT];
    int g = blockIdx.x;
    int tid = threadIdx.x;
    for (int i = tid; i < HDIM * COUT; i += 256) sW[i] = Wo[i];
    int beg = gstart[g], end = gstart[g + 1];
    int c = tid & 63, r0 = tid >> 6;
    float s0 = 0.f, s1 = 0.f, s2 = 0.f, s3 = 0.f;
    int r = beg + r0;
    for (; r + 12 < end; r += 16) {
        s0 += h[(size_t)(r     ) * HDIM + c];
        s1 += h[(size_t)(r +  4) * HDIM + c];
        s2 += h[(size_t)(r +  8) * HDIM + c];
        s3 += h[(size_t)(r + 12) * HDIM + c];
    }
    for (; r < end; r += 4) s0 += h[(size_t)r * HDIM + c];
    red[tid] = (s0 + s1) + (s2 + s3);
    __syncthreads();
    if (tid < HDIM) {
        float s = red[tid] + red[tid + 64] + red[tid + 128] + red[tid + 192];
        float cnt = (float)(end - beg);
        float pooled = s / fmaxf(cnt, 1.0f);
        sp[tid] = fmaxf(pooled, 0.0f);
    }
    __syncthreads();
    if (tid < COUT) {
        float acc = bo[tid];
#pragma unroll
        for (int k = 0; k < HDIM; k++) acc += sp[k] * sW[k * COUT + tid];
        out[g * COUT + tid] = acc;
    }
}

// ================================================================ launch
extern "C" void kernel_launch(void* const* d_in, const int* in_sizes, int n_in,
                              void* d_out, int out_size, void* d_ws, size_t ws_size,
                              hipStream_t stream) {
    (void)in_sizes; (void)n_in; (void)out_size; (void)ws_size;
    const float* x          = (const float*)d_in[0];
    const int*   eidx       = (const int*)  d_in[1];
    const float* eattr      = (const float*)d_in[2];
    const int*   batch      = (const int*)  d_in[3];
    const float* lin_in_w   = (const float*)d_in[4];
    const float* lin_in_b   = (const float*)d_in[5];
    const float* norm_gamma = (const float*)d_in[6];
    const float* norm_beta  = (const float*)d_in[7];
    const float* edge_w     = (const float*)d_in[8];
    const float* edge_b     = (const float*)d_in[9];
    const float* tparam     = (const float*)d_in[10];
    const float* mlp_w1     = (const float*)d_in[11];
    const float* mlp_b1     = (const float*)d_in[12];
    const float* mlp_gamma  = (const float*)d_in[13];
    const float* mlp_beta   = (const float*)d_in[14];
    const float* mlp_w2     = (const float*)d_in[15];
    const float* mlp_b2     = (const float*)d_in[16];
    const float* lin_out_w  = (const float*)d_in[17];
    const float* lin_out_b  = (const float*)d_in[18];
    float* out = (float*)d_out;

    const int* src = eidx;                   // edge_index[0]
    const int* dst = eidx + N_EDGES;         // edge_index[1]

    char* ws = (char*)d_ws;
    size_t off = 0;
    auto alloc = [&](size_t bytes) -> char* {
        char* p = ws + off;
        off = (off + bytes + 255) & ~(size_t)255;
        return p;
    };
    // stats first (zero region)
    float* statsA0 = (float*)alloc(128 * 4);
    float* statsB0 = (float*)alloc(256 * 4);
    float* statsA1 = (float*)alloc(128 * 4);
    float* statsB1 = (float*)alloc(256 * 4);
    size_t zero_bytes = off;
    int*   bsum    = (int*)  alloc(256 * 4);
    int4*  edge4   = (int4*) alloc((size_t)N_EDGES * 16);
    int*   gstart  = (int*)  alloc((size_t)(NGRAPH + 1) * 4);
    float* h       = (float*)alloc((size_t)N_NODES * HDIM * 4);
    float* num     = (float*)alloc((size_t)N_NODES * HDIM * 4);
    float* den     = (float*)alloc((size_t)N_NODES * HDIM * 4);   // contiguous after num
    float* h1      = (float*)alloc((size_t)N_NODES * 2 * HDIM * 4);
    // Padded cnt/cursor (3.2 MB each) ALIASED into h1: the sort pipeline
    // completes before mlp1 ever writes h1, and h1 (25.6 MB) >= 6.4 MB.
    // Keeps total workspace at the proven ~77 MB footprint.
    int*   cnt     = (int*)h1;
    int*   cursor  = (int*)((char*)h1 + (size_t)N_NODES * CPAD * 4);

    hipMemsetAsync(d_ws, 0, zero_bytes, stream);                       // stats
    hipMemsetAsync(cnt, 0, (size_t)N_NODES * CPAD * 4, stream);        // padded histogram
    // num+den zeroed once; mlp1 self-cleans them for the next layer
    hipMemsetAsync(num, 0, (size_t)N_NODES * HDIM * 4 * 2, stream);

    const int NB = (N_NODES + 255) / 256;    // 196 blocks
    const int EB4 = (N_EDGES / 4 + 255) / 256;   // 782 blocks (4 edges/thread)
    hist_kernel      <<<EB4, 256, 0, stream>>>(dst, cnt, N_EDGES);
    scan_part_kernel <<<NB, 256, 0, stream>>>(cnt, bsum, N_NODES);
    scan_top_kernel  <<<1, 256, 0, stream>>>(bsum, NB);
    scan_apply_kernel<<<NB, 256, 0, stream>>>(cnt, bsum, cursor, N_NODES);
    scatter_kernel   <<<EB4, 256, 0, stream>>>(dst, src, cursor, edge4, N_EDGES);
    gstart_kernel    <<<NB, 256, 0, stream>>>(batch, gstart, N_NODES, NGRAPH);
    lin_in_kernel    <<<(N_NODES + 3) / 4, 256, 0, stream>>>(x, lin_in_w, lin_in_b, h, N_NODES);

    const int AGG_BLOCKS = N_EDGES / 256;    // 3125, exact (4 waves x 64 edges)

    float* statsA[2] = { statsA0, statsA1 };
    float* statsB[2] = { statsB0, statsB1 };
    for (int l = 0; l < 2; l++) {
        bn_stats_kernel<64><<<256, 256, 0, stream>>>(h, statsA[l], N_NODES);
        edge_agg_kernel<<<AGG_BLOCKS, 256, 0, stream>>>(
            h, eattr, edge4,
            edge_w + (size_t)l * EDIM * HDIM, edge_b + l * HDIM,
            tparam + l, statsA[l], norm_gamma + l * HDIM, norm_beta + l * HDIM,
            num, den);
        mlp1_kernel<<<(N_NODES + 31) / 32, 256, 0, stream>>>(
            num, den, h, statsA[l], norm_gamma + l * HDIM, norm_beta + l * HDIM,
            mlp_w1 + (size_t)l * HDIM * 2 * HDIM, mlp_b1 + l * 2 * HDIM, h1, N_NODES);
        bn_stats_kernel<128><<<256, 256, 0, stream>>>(h1, statsB[l], N_NODES);
        mlp2_kernel<<<(N_NODES + 31) / 32, 256, 0, stream>>>(
            h1, statsB[l], mlp_gamma + l * 2 * HDIM, mlp_beta + l * 2 * HDIM,
            mlp_w2 + (size_t)l * 2 * HDIM * HDIM, mlp_b2 + l * HDIM, h, N_NODES);
    }
    pool_out_kernel<<<NGRAPH, 256, 0, stream>>>(h, gstart, lin_out_w, lin_out_b, out, N_NODES);
}

// Round 13
// 580.785 us; speedup vs baseline: 1.8359x; 1.0192x over previous
//
#include <hip/hip_runtime.h>

#define N_NODES 50000
#define N_EDGES 800000
#define F_INP   32
#define HDIM    64
#define EDIM    16
#define COUT    40
#define NGRAPH  64
#define LDS_STRIDE 18   // floats per staged attr row: 16 + 2 pad (keeps b64 align, spreads banks)
#define CPAD    16      // cursor/cnt padding: 1 counter per 64B line (kills same-line atomic serialization)

#define HIST_B  782     // (N_EDGES/4 + 255)/256
#define NB_B    196     // (N_NODES + 255)/256
#define LIN_B   12500   // (N_NODES + 3)/4

typedef float v2f __attribute__((ext_vector_type(2)));

// ---------------------------------------------------------------- fat kernel 1
// hist (atomic-latency-bound) || gstart || lin_in (compute) — mutually
// independent; fused so lin_in's 12.5K blocks fill hist's latency shadow
// and two dispatch boundaries disappear.
__global__ __launch_bounds__(256) void prep_kernel(
        const int* __restrict__ dst, int* __restrict__ cnt,
        const int* __restrict__ batch, int* __restrict__ gstart,
        const float* __restrict__ x, const float* __restrict__ W,
        const float* __restrict__ b, float* __restrict__ h) {
    int bid = blockIdx.x;
    int tid = threadIdx.x;
    if (bid < HIST_B) {
        // ---- hist: 4 edges/thread, int4 reads, padded counters ----
        int base = (bid * 256 + tid) * 4;
        if (base >= N_EDGES) return;
        int4 d4 = *(const int4*)(dst + base);
        atomicAdd(&cnt[(size_t)d4.x * CPAD], 1);
        atomicAdd(&cnt[(size_t)d4.y * CPAD], 1);
        atomicAdd(&cnt[(size_t)d4.z * CPAD], 1);
        atomicAdd(&cnt[(size_t)d4.w * CPAD], 1);
    } else if (bid < HIST_B + NB_B) {
        // ---- gstart: batch sorted ascending ----
        int n = (bid - HIST_B) * 256 + tid;
        if (n >= N_NODES) return;
        int g  = batch[n];
        int gp = (n == 0) ? -1 : batch[n - 1];
        for (int gg = gp + 1; gg <= g; gg++) gstart[gg] = n;
        if (n == N_NODES - 1) {
            for (int gg = g + 1; gg <= NGRAPH; gg++) gstart[gg] = N_NODES;
        }
    } else {
        // ---- lin_in: W column in regs, 4 nodes/block ----
        int c = tid & 63;
        float w[F_INP];
#pragma unroll
        for (int k = 0; k < F_INP; k++) w[k] = W[k * HDIM + c];
        int node = (bid - HIST_B - NB_B) * 4 + (tid >> 6);
        if (node >= N_NODES) return;
        const float4* xr = (const float4*)(x + (size_t)node * F_INP);
        float acc = b[c];
#pragma unroll
        for (int k4 = 0; k4 < F_INP / 4; k4++) {
            float4 xv = xr[k4];
            acc += xv.x * w[k4 * 4 + 0] + xv.y * w[k4 * 4 + 1]
                 + xv.z * w[k4 * 4 + 2] + xv.w * w[k4 * 4 + 3];
        }
        h[(size_t)node * HDIM + c] = acc;
    }
}

// ---------------------------------------------------------------- scan (2 stages)
__global__ void scan_part_kernel(const int* __restrict__ cnt, int* __restrict__ bsum, int n) {
    __shared__ int red[256];
    int tid = threadIdx.x;
    int idx = blockIdx.x * 256 + tid;
    red[tid] = (idx < n) ? cnt[(size_t)idx * CPAD] : 0;
    __syncthreads();
    for (int off = 128; off > 0; off >>= 1) {
        if (tid < off) red[tid] += red[tid + off];
        __syncthreads();
    }
    if (tid == 0) bsum[blockIdx.x] = red[0];
}

// apply with INLINE top-scan: each block reduces bsum[0..bid) itself
// (196 ints — trivial) — the 1-block scan_top dispatch is gone.
__global__ void scan_apply_kernel(const int* __restrict__ cnt, const int* __restrict__ bsum,
                                  int* __restrict__ cursor, int n) {
    __shared__ int tmp[256];
    __shared__ int rb[256];
    int tid = threadIdx.x;
    int bb = 0;
    for (int j = tid; j < blockIdx.x; j += 256) bb += bsum[j];
    rb[tid] = bb;
    __syncthreads();
    for (int off = 128; off > 0; off >>= 1) {
        if (tid < off) rb[tid] += rb[tid + off];
        __syncthreads();
    }
    int base = rb[0];
    int idx = blockIdx.x * 256 + tid;
    int v = (idx < n) ? cnt[(size_t)idx * CPAD] : 0;
    tmp[tid] = v;
    __syncthreads();
    for (int off = 1; off < 256; off <<= 1) {
        int x = (tid >= off) ? tmp[tid - off] : 0;
        __syncthreads();
        tmp[tid] += x;
        __syncthreads();
    }
    int excl = tmp[tid] - v + base;
    if (idx < n) cursor[(size_t)idx * CPAD] = excl;
}

// ---------------------------------------------------------------- fat kernel 2
// scatter (atomic-latency-bound) || bn_stats<64> layer-0 (BW-bound, ~10us)
// — independent (scatter needs cursor, bn needs h); bn hides under scatter.
__global__ __launch_bounds__(256) void scatter_bn_kernel(
        const int* __restrict__ dst, const int* __restrict__ src,
        int* __restrict__ cursor, int4* __restrict__ edge4,
        const float* __restrict__ h, float* __restrict__ stats) {
    __shared__ float ls[256], lss[256];
    int bid = blockIdx.x;
    int tid = threadIdx.x;
    if (bid < HIST_B) {
        // ---- scatter: 4 edges/thread, packed int4 rows ----
        int base = (bid * 256 + tid) * 4;
        if (base >= N_EDGES) return;
        int4 d4 = *(const int4*)(dst + base);
        int4 s4 = *(const int4*)(src + base);
        int p0 = atomicAdd(&cursor[(size_t)d4.x * CPAD], 1);
        int p1 = atomicAdd(&cursor[(size_t)d4.y * CPAD], 1);
        int p2 = atomicAdd(&cursor[(size_t)d4.z * CPAD], 1);
        int p3 = atomicAdd(&cursor[(size_t)d4.w * CPAD], 1);
        edge4[p0] = make_int4(d4.x, s4.x, base + 0, 0);
        edge4[p1] = make_int4(d4.y, s4.y, base + 1, 0);
        edge4[p2] = make_int4(d4.z, s4.z, base + 2, 0);
        edge4[p3] = make_int4(d4.w, s4.w, base + 3, 0);
    } else {
        // ---- bn_stats<64> over h (virtual grid of 256 blocks) ----
        int vb = bid - HIST_B;               // 0..255
        int c = tid & 63;
        int row0 = vb * 4 + (tid >> 6);
        float s = 0.f, ss = 0.f;
        for (int r = row0; r < N_NODES; r += 1024) {
            float v = h[(size_t)r * HDIM + c];
            s += v; ss += v * v;
        }
        ls[tid] = s; lss[tid] = ss;
        __syncthreads();
        if (tid < 64) {
            float ts  = ls[tid] + ls[tid + 64] + ls[tid + 128] + ls[tid + 192];
            float tss = lss[tid] + lss[tid + 64] + lss[tid + 128] + lss[tid + 192];
            atomicAdd(&stats[c], ts);
            atomicAdd(&stats[HDIM + c], tss);
        }
    }
}

// ---------------------------------------------------------------- BN stats (standalone)
template <int C>
__global__ void bn_stats_kernel(const float* __restrict__ x, float* __restrict__ stats, int N) {
    const int RPB = 256 / C;
    int tid = threadIdx.x;
    int c = tid % C;
    int row0 = blockIdx.x * RPB + tid / C;
    int stride = gridDim.x * RPB;
    float s = 0.f, ss = 0.f;
    for (int r = row0; r < N; r += stride) {
        float v = x[(size_t)r * C + c];
        s += v; ss += v * v;
    }
    __shared__ float ls[256], lss[256];
    ls[tid] = s; lss[tid] = ss;
    __syncthreads();
    if (tid < C) {
        for (int k = 1; k < RPB; k++) { s += ls[tid + k * C]; ss += lss[tid + k * C]; }
        atomicAdd(&stats[c], s);
        atomicAdd(&stats[C + c], ss);
    }
}

// ---------------------------------------------------------------- edge-parallel aggregation
// One wave per 64 contiguous dst-sorted positions; ONE EDGE PER LANE.
// Attr rows staged in LDS; broadcast via same-address ds_read_b64 (DS pipe).
// pk_fma dot, ballot boundary mask (SALU in-loop test), 8-edge rolled body.
// Sorted order is essential: amortized flush = ~32 MB atomic traffic vs
// 400 MB unsorted (round-11 measured, 5x slower). Keep sort.
__global__ __launch_bounds__(256) void edge_agg_kernel(
        const float* __restrict__ h, const float* __restrict__ ea,
        const int4* __restrict__ edge4,
        const float* __restrict__ We, const float* __restrict__ be,
        const float* __restrict__ tptr, const float* __restrict__ stats,
        const float* __restrict__ gamma, const float* __restrict__ beta,
        float* __restrict__ num, float* __restrict__ den) {
    __shared__ float sA[4 * 64 * LDS_STRIDE];    // 4 waves x 64 edges x 18 f = 18 KB
    int tid = threadIdx.x;
    int c  = tid & 63;                       // channel == lane
    int wv = tid >> 6;
    // BN folded: z = relu(h*sc + sb)
    float inv = 1.0f / (float)N_NODES;
    float mu  = stats[c] * inv;
    float var = stats[HDIM + c] * inv - mu * mu;
    float sc  = rsqrtf(var + 1e-5f) * gamma[c];
    float sb  = beta[c] - mu * sc;
    v2f w2[8];
#pragma unroll
    for (int k = 0; k < 8; k++) {
        w2[k].x = We[(2 * k) * HDIM + c];
        w2[k].y = We[(2 * k + 1) * HDIM + c];
    }
    float bc = be[c];
    float tl2 = (*tptr) * 1.4426950408889634f;   // t * log2(e)

    // this lane's own edge (position p in sorted order)
    int p = (blockIdx.x * 4 + wv) * 64 + c;      // grid sized so p < E always
    int4 pk = edge4[p];                          // one coalesced dwordx4
    int d_own = pk.x;
    int s_own = pk.y;
    int e     = pk.z;
    // stage own attr row to LDS
    float* myrow = &sA[(wv * 64 + c) * LDS_STRIDE];
    {
        const float4* ar = (const float4*)(ea + (size_t)e * EDIM);
        float4 a0 = ar[0], a1 = ar[1], a2 = ar[2], a3 = ar[3];
        myrow[0]=a0.x;  myrow[1]=a0.y;  myrow[2]=a0.z;  myrow[3]=a0.w;
        myrow[4]=a1.x;  myrow[5]=a1.y;  myrow[6]=a1.z;  myrow[7]=a1.w;
        myrow[8]=a2.x;  myrow[9]=a2.y;  myrow[10]=a2.z; myrow[11]=a2.w;
        myrow[12]=a3.x; myrow[13]=a3.y; myrow[14]=a3.z; myrow[15]=a3.w;
    }
    // boundary mask: bit u set iff dst changes at chunk position u (u>0)
    int dprev = __shfl_up(d_own, 1);
    unsigned long long bmask = __ballot(c > 0 && d_own != dprev);
    __syncthreads();                         // staging visible (per-wave use only)

    const float* wrow = &sA[(size_t)wv * 64 * LDS_STRIDE];
    float nacc = 0.f, dacc = 0.f;
    int cur_d = __builtin_amdgcn_readlane(d_own, 0);
#pragma unroll 1
    for (int jj = 0; jj < 64; jj += 8) {
        // issue 8 h-row gathers ahead (independent vector loads)
        float hv[8];
#pragma unroll
        for (int u = 0; u < 8; u++) {
            int su = __builtin_amdgcn_readlane(s_own, jj + u);
            hv[u] = h[(size_t)su * HDIM + c];
        }
#pragma unroll
        for (int u = 0; u < 8; u++) {
            if (bmask & (1ull << (jj + u))) {    // SALU test, wave-uniform
                atomicAdd(&num[(size_t)cur_d * HDIM + c], nacc);
                atomicAdd(&den[(size_t)cur_d * HDIM + c], dacc);
                nacc = 0.f; dacc = 0.f;
                cur_d = __builtin_amdgcn_readlane(d_own, jj + u);
            }
            // broadcast attr row via same-address ds_read_b64 (DS pipe)
            const v2f* arow = (const v2f*)&wrow[(jj + u) * LDS_STRIDE];
            v2f acc2 = {bc, 0.f};
#pragma unroll
            for (int k2 = 0; k2 < 8; k2++)
                acc2 += arow[k2] * w2[k2];       // v_pk_fma_f32
            float acc = acc2.x + acc2.y;
            float zv = fmaxf(hv[u] * sc + sb, 0.f);
            float m  = fmaxf(zv + acc, 0.f) + 1e-7f;
            float ex = exp2f(m * tl2);
            dacc += ex;
            nacc += ex * m;
        }
    }
    atomicAdd(&num[(size_t)cur_d * HDIM + c], nacc);
    atomicAdd(&den[(size_t)cur_d * HDIM + c], dacc);
}

// ---------------------------------------------------------------- MLP part 1
// Fused finalize: in = num/(den+eps) + relu(BN(h)); also self-cleans num/den
// to zero for the next layer (each idx touched exactly once).
__global__ __launch_bounds__(256) void mlp1_kernel(
        float* __restrict__ num, float* __restrict__ den,
        const float* __restrict__ h, const float* __restrict__ stats,
        const float* __restrict__ gamma, const float* __restrict__ beta,
        const float* __restrict__ W1, const float* __restrict__ b1,
        float* __restrict__ h1, int N) {
    __shared__ float sW[HDIM * 128];         // 32 KB
    __shared__ float srow[32 * 65];          // +1 pad breaks bank stride
    int tid = threadIdx.x;
    for (int i = tid; i < HDIM * 128; i += 256) sW[i] = W1[i];
    int base = blockIdx.x * 32;
    {
        int cc = tid & 63;                   // constant across the i-loop (256%64==0)
        float inv = 1.0f / (float)N_NODES;
        float mu  = stats[cc] * inv;
        float var = stats[HDIM + cc] * inv - mu * mu;
        float rs  = rsqrtf(var + 1e-5f);
        float ga  = gamma[cc], bb = beta[cc];
        for (int i = tid; i < 32 * HDIM; i += 256) {
            int r = i >> 6;
            int node = base + r;
            float v = 0.f;
            if (node < N) {
                size_t idx = (size_t)node * HDIM + cc;
                float hv = h[idx];
                float z  = fmaxf((hv - mu) * rs * ga + bb, 0.f);
                float nu = num[idx], de = den[idx];
                num[idx] = 0.f; den[idx] = 0.f;   // ready for next layer
                v = nu / (de + 1e-16f) + z;
            }
            srow[r * 65 + cc] = v;
        }
    }
    __syncthreads();
    int tx = tid & 31;                       // outputs 4*tx .. 4*tx+3
    int ty = tid >> 5;                       // nodes ty*4 .. ty*4+3
    float acc[4][4];
    float b0 = b1[4 * tx], bb1 = b1[4 * tx + 1], b2v = b1[4 * tx + 2], b3 = b1[4 * tx + 3];
#pragma unroll
    for (int j = 0; j < 4; j++) { acc[j][0] = b0; acc[j][1] = bb1; acc[j][2] = b2v; acc[j][3] = b3; }
#pragma unroll 8
    for (int k = 0; k < HDIM; k++) {
        float4 wv = *(const float4*)&sW[k * 128 + 4 * tx];
        float r0 = srow[(ty * 4 + 0) * 65 + k];
        float r1 = srow[(ty * 4 + 1) * 65 + k];
        float r2 = srow[(ty * 4 + 2) * 65 + k];
        float r3 = srow[(ty * 4 + 3) * 65 + k];
        acc[0][0] += r0 * wv.x; acc[0][1] += r0 * wv.y; acc[0][2] += r0 * wv.z; acc[0][3] += r0 * wv.w;
        acc[1][0] += r1 * wv.x; acc[1][1] += r1 * wv.y; acc[1][2] += r1 * wv.z; acc[1][3] += r1 * wv.w;
        acc[2][0] += r2 * wv.x; acc[2][1] += r2 * wv.y; acc[2][2] += r2 * wv.z; acc[2][3] += r2 * wv.w;
        acc[3][0] += r3 * wv.x; acc[3][1] += r3 * wv.y; acc[3][2] += r3 * wv.z; acc[3][3] += r3 * wv.w;
    }
#pragma unroll
    for (int j = 0; j < 4; j++) {
        int node = base + ty * 4 + j;
        if (node < N)
            *(float4*)&h1[(size_t)node * 128 + 4 * tx] =
                make_float4(acc[j][0], acc[j][1], acc[j][2], acc[j][3]);
    }
}

// ---------------------------------------------------------------- MLP part 2
__global__ __launch_bounds__(256) void mlp2_kernel(
        const float* __restrict__ h1, const float* __restrict__ stats,
        const float* __restrict__ mg, const float* __restrict__ mb,
        const float* __restrict__ W2, const float* __restrict__ b2,
        float* __restrict__ h, int N) {
    __shared__ float sW[128 * HDIM];         // 32 KB
    __shared__ float sact[32 * 129];         // 16.5 KB, +1 pad
    __shared__ float sbn[4 * 128];           // mu, rs, gamma, beta
    int tid = threadIdx.x;
    for (int i = tid; i < 128 * HDIM; i += 256) sW[i] = W2[i];
    if (tid < 128) {
        float inv = 1.0f / (float)N;
        float mu  = stats[tid] * inv;
        float var = stats[128 + tid] * inv - mu * mu;
        sbn[tid]       = mu;
        sbn[128 + tid] = rsqrtf(var + 1e-5f);
        sbn[256 + tid] = mg[tid];
        sbn[384 + tid] = mb[tid];
    }
    __syncthreads();
    int base = blockIdx.x * 32;
    for (int i = tid; i < 32 * 128; i += 256) {
        int r = i >> 7, o = i & 127;
        int node = base + r;
        float v = 0.f;
        if (node < N) {
            v = h1[(size_t)node * 128 + o];
            v = fmaxf((v - sbn[o]) * sbn[128 + o] * sbn[256 + o] + sbn[384 + o], 0.f);
        }
        sact[r * 129 + o] = v;
    }
    __syncthreads();
    int tx = tid & 15;                       // outputs 4*tx .. 4*tx+3
    int ty = tid >> 4;                       // nodes ty*2, ty*2+1
    float acc[2][4];
    float b0 = b2[4 * tx], bb1 = b2[4 * tx + 1], b2v = b2[4 * tx + 2], b3 = b2[4 * tx + 3];
    acc[0][0] = b0; acc[0][1] = bb1; acc[0][2] = b2v; acc[0][3] = b3;
    acc[1][0] = b0; acc[1][1] = bb1; acc[1][2] = b2v; acc[1][3] = b3;
#pragma unroll 8
    for (int k = 0; k < 128; k++) {
        float4 wv = *(const float4*)&sW[k * HDIM + 4 * tx];
        float r0 = sact[(ty * 2 + 0) * 129 + k];
        float r1 = sact[(ty * 2 + 1) * 129 + k];
        acc[0][0] += r0 * wv.x; acc[0][1] += r0 * wv.y; acc[0][2] += r0 * wv.z; acc[0][3] += r0 * wv.w;
        acc[1][0] += r1 * wv.x; acc[1][1] += r1 * wv.y; acc[1][2] += r1 * wv.z; acc[1][3] += r1 * wv.w;
    }
#pragma unroll
    for (int j = 0; j < 2; j++) {
        int node = base + ty * 2 + j;
        if (node < N) {
            float4* p = (float4*)&h[(size_t)node * HDIM + 4 * tx];
            float4 old = *p;
            *p = make_float4(old.x + acc[j][0], old.y + acc[j][1],
                             old.z + acc[j][2], old.w + acc[j][3]);
        }
    }
}

// ---------------------------------------------------------------- pool + head
// 4 independent accumulators quarter the dependent-load chain (round-12 win).
__global__ void pool_out_kernel(const float* __restrict__ h, const int* __restrict__ gstart,
                                const float* __restrict__ Wo, const float* __restrict__ bo,
                                float* __restrict__ out, int N) {
    __shared__ float sp[HDIM];
    __shared__ float red[256];
    __shared__ float sW[HDIM * COUT];
    int g = blockIdx.x;
    int tid = threadIdx.x;
    for (int i = tid; i < HDIM * COUT; i += 256) sW[i] = Wo[i];
    int beg = gstart[g], end = gstart[g + 1];
    int c = tid & 63, r0 = tid >> 6;
    float s0 = 0.f, s1 = 0.f, s2 = 0.f, s3 = 0.f;
    int r = beg + r0;
    for (; r + 12 < end; r += 16) {
        s0 += h[(size_t)(r     ) * HDIM + c];
        s1 += h[(size_t)(r +  4) * HDIM + c];
        s2 += h[(size_t)(r +  8) * HDIM + c];
        s3 += h[(size_t)(r + 12) * HDIM + c];
    }
    for (; r < end; r += 4) s0 += h[(size_t)r * HDIM + c];
    red[tid] = (s0 + s1) + (s2 + s3);
    __syncthreads();
    if (tid < HDIM) {
        float s = red[tid] + red[tid + 64] + red[tid + 128] + red[tid + 192];
        float cnt = (float)(end - beg);
        float pooled = s / fmaxf(cnt, 1.0f);
        sp[tid] = fmaxf(pooled, 0.0f);
    }
    __syncthreads();
    if (tid < COUT) {
        float acc = bo[tid];
#pragma unroll
        for (int k = 0; k < HDIM; k++) acc += sp[k] * sW[k * COUT + tid];
        out[g * COUT + tid] = acc;
    }
}

// ================================================================ launch
extern "C" void kernel_launch(void* const* d_in, const int* in_sizes, int n_in,
                              void* d_out, int out_size, void* d_ws, size_t ws_size,
                              hipStream_t stream) {
    (void)in_sizes; (void)n_in; (void)out_size; (void)ws_size;
    const float* x          = (const float*)d_in[0];
    const int*   eidx       = (const int*)  d_in[1];
    const float* eattr      = (const float*)d_in[2];
    const int*   batch      = (const int*)  d_in[3];
    const float* lin_in_w   = (const float*)d_in[4];
    const float* lin_in_b   = (const float*)d_in[5];
    const float* norm_gamma = (const float*)d_in[6];
    const float* norm_beta  = (const float*)d_in[7];
    const float* edge_w     = (const float*)d_in[8];
    const float* edge_b     = (const float*)d_in[9];
    const float* tparam     = (const float*)d_in[10];
    const float* mlp_w1     = (const float*)d_in[11];
    const float* mlp_b1     = (const float*)d_in[12];
    const float* mlp_gamma  = (const float*)d_in[13];
    const float* mlp_beta   = (const float*)d_in[14];
    const float* mlp_w2     = (const float*)d_in[15];
    const float* mlp_b2     = (const float*)d_in[16];
    const float* lin_out_w  = (const float*)d_in[17];
    const float* lin_out_b  = (const float*)d_in[18];
    float* out = (float*)d_out;

    const int* src = eidx;                   // edge_index[0]
    const int* dst = eidx + N_EDGES;         // edge_index[1]

    char* ws = (char*)d_ws;
    size_t off = 0;
    auto alloc = [&](size_t bytes) -> char* {
        char* p = ws + off;
        off = (off + bytes + 255) & ~(size_t)255;
        return p;
    };
    // stats first (zero region)
    float* statsA0 = (float*)alloc(128 * 4);
    float* statsB0 = (float*)alloc(256 * 4);
    float* statsA1 = (float*)alloc(128 * 4);
    float* statsB1 = (float*)alloc(256 * 4);
    size_t zero_bytes = off;
    int*   bsum    = (int*)  alloc(256 * 4);
    int4*  edge4   = (int4*) alloc((size_t)N_EDGES * 16);
    int*   gstart  = (int*)  alloc((size_t)(NGRAPH + 1) * 4);
    float* h       = (float*)alloc((size_t)N_NODES * HDIM * 4);
    float* num     = (float*)alloc((size_t)N_NODES * HDIM * 4);
    float* den     = (float*)alloc((size_t)N_NODES * HDIM * 4);   // contiguous after num
    float* h1      = (float*)alloc((size_t)N_NODES * 2 * HDIM * 4);
    // Padded cnt/cursor (3.2 MB each) ALIASED into h1: the sort pipeline
    // completes before mlp1 ever writes h1, and h1 (25.6 MB) >= 6.4 MB.
    // Keeps total workspace at the proven ~77 MB footprint.
    int*   cnt     = (int*)h1;
    int*   cursor  = (int*)((char*)h1 + (size_t)N_NODES * CPAD * 4);

    hipMemsetAsync(d_ws, 0, zero_bytes, stream);                       // stats
    hipMemsetAsync(cnt, 0, (size_t)N_NODES * CPAD * 4, stream);        // padded histogram
    // num+den zeroed once; mlp1 self-cleans them for the next layer
    hipMemsetAsync(num, 0, (size_t)N_NODES * HDIM * 4 * 2, stream);

    // prep: hist || gstart || lin_in in one dispatch
    prep_kernel      <<<HIST_B + NB_B + LIN_B, 256, 0, stream>>>(
        dst, cnt, batch, gstart, x, lin_in_w, lin_in_b, h);
    scan_part_kernel <<<NB_B, 256, 0, stream>>>(cnt, bsum, N_NODES);
    scan_apply_kernel<<<NB_B, 256, 0, stream>>>(cnt, bsum, cursor, N_NODES);
    // scatter || bn_stats<64>(layer 0) in one dispatch
    scatter_bn_kernel<<<HIST_B + 256, 256, 0, stream>>>(
        dst, src, cursor, edge4, h, statsA0);

    const int AGG_BLOCKS = N_EDGES / 256;    // 3125, exact (4 waves x 64 edges)

    float* statsA[2] = { statsA0, statsA1 };
    float* statsB[2] = { statsB0, statsB1 };
    for (int l = 0; l < 2; l++) {
        if (l == 1)
            bn_stats_kernel<64><<<256, 256, 0, stream>>>(h, statsA1, N_NODES);
        edge_agg_kernel<<<AGG_BLOCKS, 256, 0, stream>>>(
            h, eattr, edge4,
            edge_w + (size_t)l * EDIM * HDIM, edge_b + l * HDIM,
            tparam + l, statsA[l], norm_gamma + l * HDIM, norm_beta + l * HDIM,
            num, den);
        mlp1_kernel<<<(N_NODES + 31) / 32, 256, 0, stream>>>(
            num, den, h, statsA[l], norm_gamma + l * HDIM, norm_beta + l * HDIM,
            mlp_w1 + (size_t)l * HDIM * 2 * HDIM, mlp_b1 + l * 2 * HDIM, h1, N_NODES);
        bn_stats_kernel<128><<<256, 256, 0, stream>>>(h1, statsB[l], N_NODES);
        mlp2_kernel<<<(N_NODES + 31) / 32, 256, 0, stream>>>(
            h1, statsB[l], mlp_gamma + l * 2 * HDIM, mlp_beta + l * 2 * HDIM,
            mlp_w2 + (size_t)l * 2 * HDIM * HDIM, mlp_b2 + l * HDIM, h, N_NODES);
    }
    pool_out_kernel<<<NGRAPH, 256, 0, stream>>>(h, gstart, lin_out_w, lin_out_b, out, N_NODES);
}